// Round 8
// baseline (558.066 us; speedup 1.0000x reference)
//
#include <hip/hip_runtime.h>
#include <math.h>

#define HIDDEN 768
#define KEY    128
#define INTER  1536
#define NB     4
#define SEQ    2048
#define MTOT   (NB*SEQ)          // 8192
#define ETOT   (2*INTER+KEY)     // 3200
#define CS     136               // C-tile LDS stride in halfwords

typedef short bf16x8 __attribute__((ext_vector_type(8)));
typedef float f32x4  __attribute__((ext_vector_type(4)));
typedef unsigned short u16x8 __attribute__((ext_vector_type(8)));

__device__ __forceinline__ unsigned short f2bfbits(float x) {
    union { float f; unsigned int u; } a; a.f = x;
    unsigned int r = a.u + 0x7fffu + ((a.u >> 16) & 1u);
    return (unsigned short)(r >> 16);
}
__device__ __forceinline__ float bfbits2f(unsigned short b) {
    union { float f; unsigned int u; } a; a.u = ((unsigned int)b) << 16;
    return a.f;
}

// ---- fused prologue: X->bf16, Wi^T, Wo^T, per-batch scale ----
__device__ __forceinline__ void transpose_tile(
    const float* __restrict__ in, unsigned short* __restrict__ out,
    int R, int C, int c0, int r0, int tid, unsigned short tile[32][33])
{
    int tx = tid & 31, ty4 = (tid >> 5)*4;
    #pragma unroll
    for (int rr = 0; rr < 4; rr++) {
        int r = ty4 + rr;
        tile[r][tx] = f2bfbits(in[(size_t)(r0+r)*C + c0+tx]);
    }
    __syncthreads();
    #pragma unroll
    for (int rr = 0; rr < 4; rr++) {
        int r = ty4 + rr;
        out[(size_t)(c0+r)*R + r0+tx] = tile[tx][r];
    }
}

__global__ __launch_bounds__(256) void prep_kernel(
    const float* __restrict__ X, const float* __restrict__ Wi,
    const float* __restrict__ Wo, const int* __restrict__ mask,
    unsigned short* __restrict__ Xb, unsigned short* __restrict__ WiT,
    unsigned short* __restrict__ WoT, float* __restrict__ scaleb)
{
    __shared__ unsigned short tile[32][33];
    __shared__ int red[256];
    const int bid = blockIdx.x, tid = threadIdx.x;
    if (bid < 3072) {                          // X -> bf16, 8 elems/thread
        int i = bid*256 + tid;
        const float4* in4 = (const float4*)X;
        float4 a = in4[(size_t)i*2], b = in4[(size_t)i*2+1];
        u16x8 o;
        o[0]=f2bfbits(a.x); o[1]=f2bfbits(a.y); o[2]=f2bfbits(a.z); o[3]=f2bfbits(a.w);
        o[4]=f2bfbits(b.x); o[5]=f2bfbits(b.y); o[6]=f2bfbits(b.z); o[7]=f2bfbits(b.w);
        *(u16x8*)&Xb[(size_t)i*8] = o;
    } else if (bid < 5472) {                   // Wi [768][3200] -> WiT [3200][768]
        int t = bid - 3072;
        transpose_tile(Wi, WiT, HIDDEN, ETOT, (t%100)*32, (t/100)*32, tid, tile);
    } else if (bid < 6624) {                   // Wo [1536][768] -> WoT [768][1536]
        int t = bid - 5472;
        transpose_tile(Wo, WoT, INTER, HIDDEN, (t%24)*32, (t/24)*32, tid, tile);
    } else {                                   // per-batch softmax length scale
        int b = bid - 6624;
        int s = 0;
        for (int j = tid; j < SEQ; j += 256)
            s += (mask[b*SEQ + j] != 0) ? 1 : 0;
        red[tid] = s;
        __syncthreads();
        for (int step = 128; step > 0; step >>= 1) {
            if (tid < step) red[tid] += red[tid + step];
            __syncthreads();
        }
        if (tid == 0) {
            float l = fmaxf((float)red[0], 1.0f);
            scaleb[b] = logf(l) / logf(512.0f);
        }
    }
}

// ---- barrier-free direct-register MFMA K-loop ----
// A and B^T both [row][K] bf16; each lane loads its own 16B fragments straight
// from global (L2-resident via XCD swizzle). Ping-pong frag buffers: loads for
// the next half-iteration issue before the MFMAs of the current one, so the
// compiler can hide L2 latency with MFMA work (no __syncthreads in the loop).
// NJ = B-frag count (4 -> 128-wide tile, 2 -> 64-wide).
template<int NJ>
__device__ __forceinline__ void mfma_direct(
    const unsigned short* __restrict__ A, int lda,
    const unsigned short* __restrict__ B, int ldb,
    f32x4 acc[4][NJ], int tid, int ktot)
{
    const int lane = tid & 63, wave = tid >> 6;
    const int wm = (wave >> 1) << 6;
    const int wn = (wave & 1) * (NJ * 16);
    const int lm = lane & 15, q8 = (lane >> 4) << 3;
    const unsigned short* pa[4];
    const unsigned short* pb[NJ];
    #pragma unroll
    for (int i = 0; i < 4; i++) pa[i] = A + (size_t)(wm + i*16 + lm)*lda + q8;
    #pragma unroll
    for (int j = 0; j < NJ; j++) pb[j] = B + (size_t)(wn + j*16 + lm)*ldb + q8;

    bf16x8 ac[4], bc[NJ], an[4], bn[NJ];
    #pragma unroll
    for (int i = 0; i < 4; i++) ac[i] = *(const bf16x8*)(pa[i]);
    #pragma unroll
    for (int j = 0; j < NJ; j++) bc[j] = *(const bf16x8*)(pb[j]);

    for (int k0 = 0; k0 < ktot; k0 += 64) {
        // prefetch half-iter k0+32
        #pragma unroll
        for (int i = 0; i < 4; i++) an[i] = *(const bf16x8*)(pa[i] + k0 + 32);
        #pragma unroll
        for (int j = 0; j < NJ; j++) bn[j] = *(const bf16x8*)(pb[j] + k0 + 32);
        // compute on k0
        #pragma unroll
        for (int i = 0; i < 4; i++)
            #pragma unroll
            for (int j = 0; j < NJ; j++)
                acc[i][j] = __builtin_amdgcn_mfma_f32_16x16x32_bf16(ac[i], bc[j], acc[i][j], 0, 0, 0);
        // prefetch k0+64 (next loop iter)
        if (k0 + 64 < ktot) {
            #pragma unroll
            for (int i = 0; i < 4; i++) ac[i] = *(const bf16x8*)(pa[i] + k0 + 64);
            #pragma unroll
            for (int j = 0; j < NJ; j++) bc[j] = *(const bf16x8*)(pb[j] + k0 + 64);
        }
        // compute on k0+32
        #pragma unroll
        for (int i = 0; i < 4; i++)
            #pragma unroll
            for (int j = 0; j < NJ; j++)
                acc[i][j] = __builtin_amdgcn_mfma_f32_16x16x32_bf16(an[i], bn[j], acc[i][j], 0, 0, 0);
    }
}

#define EPILOG_IDX \
    const int lane = tid & 63, wave = tid >> 6; \
    const int wm = (wave >> 1) << 6, wn = (wave & 1) << 6; \
    const int cn = lane & 15, r4 = (lane >> 4) << 2;

// ---- K1: h = silu(X@Wi + bi); u row-major, vT transposed, q/k ----
// 1D grid 1600, XCD swizzle: 8-row strip per XCD, x-outer/y-inner.
__global__ __launch_bounds__(256) void gemm1_mfma(
    const unsigned short* __restrict__ Xb, const unsigned short* __restrict__ WiT,
    const float* __restrict__ bi, const float* __restrict__ gamma, const float* __restrict__ beta,
    unsigned short* __restrict__ u, unsigned short* __restrict__ vT,
    unsigned short* __restrict__ qb, unsigned short* __restrict__ kb)
{
    __shared__ __align__(16) unsigned short smem[128*CS];   // epilogue C-tile only
    const int tid = threadIdx.x;
    const int bid = blockIdx.x;
    const int xcd = bid & 7, slot = bid >> 3;
    const int xt = slot >> 3;                     // 0..24
    const int yt = (xcd << 3) + (slot & 7);       // 0..63
    const int row0 = yt*128, col0 = xt*128;
    f32x4 acc[4][4];
    #pragma unroll
    for (int i = 0; i < 4; i++)
        #pragma unroll
        for (int j = 0; j < 4; j++)
            acc[i][j] = (f32x4){0.f,0.f,0.f,0.f};
    mfma_direct<4>(Xb + (size_t)row0*HIDDEN, HIDDEN, WiT + (size_t)col0*HIDDEN, HIDDEN,
                   acc, tid, HIDDEN);
    EPILOG_IDX
    #pragma unroll
    for (int j = 0; j < 4; j++) {
        int nl = wn + j*16 + cn;
        float bin = bi[col0 + nl];
        #pragma unroll
        for (int i = 0; i < 4; i++) {
            #pragma unroll
            for (int r = 0; r < 4; r++) {
                int rowl = wm + i*16 + r4 + r;
                float x = acc[i][j][r] + bin;
                float h = x / (1.0f + __expf(-x));
                smem[rowl*CS + nl] = f2bfbits(h);
            }
        }
    }
    __syncthreads();
    if (col0 < INTER) {                       // u, row-major
        #pragma unroll
        for (int rnd = 0; rnd < 8; rnd++) {
            int row = rnd*16 + (tid>>4);
            int col = (tid&15)*8;
            u16x8 h = *(const u16x8*)&smem[row*CS + col];
            *(u16x8*)&u[(size_t)(row0+row)*INTER + col0 + col] = h;
        }
    } else if (col0 < 2*INTER) {              // v -> vT[b][INTER][SEQ]
        int c = tid >> 1;
        int half = tid & 1;
        int b = row0 / SEQ;
        int srow = row0 - b*SEQ + half*64;
        size_t base = ((size_t)b*INTER + (col0 - INTER) + c)*SEQ + srow;
        #pragma unroll
        for (int k = 0; k < 8; k++) {
            u16x8 h;
            #pragma unroll
            for (int t = 0; t < 8; t++)
                h[t] = smem[(half*64 + k*8 + t)*CS + c];
            *(u16x8*)&vT[base + k*8] = h;
        }
    } else {                                  // q/k block
        #pragma unroll
        for (int rnd = 0; rnd < 8; rnd++) {
            int row = rnd*16 + (tid>>4);
            int col = (tid&15)*8;
            u16x8 h = *(const u16x8*)&smem[row*CS + col];
            int m = row0 + row;
            u16x8 qo, ko;
            #pragma unroll
            for (int t = 0; t < 8; t++) {
                float hv = bfbits2f(h[t]);
                qo[t] = f2bfbits(hv*gamma[col+t]     + beta[col+t]);
                ko[t] = f2bfbits(hv*gamma[KEY+col+t] + beta[KEY+col+t]);
            }
            *(u16x8*)&qb[(size_t)m*KEY + col] = qo;
            *(u16x8*)&kb[(size_t)m*KEY + col] = ko;
        }
    }
}

// ---- K2: P = exp(scale * q@k^T) masked, bf16 + per-tile partial row sums ----
__global__ __launch_bounds__(256) void attn_mfma(
    const unsigned short* __restrict__ qb, const unsigned short* __restrict__ kb,
    const int* __restrict__ mask, const float* __restrict__ scaleb,
    unsigned short* __restrict__ P, float* __restrict__ lpart)
{
    __shared__ __align__(16) unsigned short smem[128*CS];
    const int tid = threadIdx.x;
    const int z = blockIdx.z;
    const int row0 = blockIdx.y*128, col0 = blockIdx.x*128;
    f32x4 acc[4][4];
    #pragma unroll
    for (int i = 0; i < 4; i++)
        #pragma unroll
        for (int j = 0; j < 4; j++)
            acc[i][j] = (f32x4){0.f,0.f,0.f,0.f};
    mfma_direct<4>(qb + ((size_t)z*SEQ + row0)*KEY, KEY, kb + ((size_t)z*SEQ + col0)*KEY, KEY,
                   acc, tid, KEY);
    const float st = scaleb[z] * 0.08838834764831845f;
    EPILOG_IDX
    #pragma unroll
    for (int j = 0; j < 4; j++) {
        int nl = wn + j*16 + cn;
        float mkf = (mask[z*SEQ + col0 + nl] != 0) ? 1.0f : 0.0f;
        #pragma unroll
        for (int i = 0; i < 4; i++) {
            #pragma unroll
            for (int r = 0; r < 4; r++) {
                int rowl = wm + i*16 + r4 + r;
                float p = mkf * __expf(acc[i][j][r]*st);
                smem[rowl*CS + nl] = f2bfbits(p);
            }
        }
    }
    __syncthreads();
    #pragma unroll
    for (int rnd = 0; rnd < 8; rnd++) {
        int row = rnd*16 + (tid>>4);
        int col = (tid&15)*8;
        u16x8 h = *(const u16x8*)&smem[row*CS + col];
        *(u16x8*)&P[((size_t)z*SEQ + row0 + row)*SEQ + col0 + col] = h;
        float s8 = 0.f;
        #pragma unroll
        for (int t = 0; t < 8; t++) s8 += bfbits2f(h[t]);
        #pragma unroll
        for (int off = 8; off > 0; off >>= 1) s8 += __shfl_xor(s8, off, 16);
        if ((tid & 15) == 0)
            lpart[(size_t)blockIdx.x*MTOT + (size_t)z*SEQ + row0 + row] = s8;
    }
}

// ---- K3: ctx = P@v / l; g = u*ctx in-place over u. XCD 4y x 6x rect ----
__global__ __launch_bounds__(256) void pv_mfma(
    const unsigned short* __restrict__ P, const unsigned short* __restrict__ vT,
    const float* __restrict__ lpart, unsigned short* __restrict__ u)
{
    __shared__ __align__(16) unsigned short smem[128*CS];
    __shared__ float ls[128];
    const int tid = threadIdx.x;
    const int bid = blockIdx.x;
    const int xcd = bid & 7, slot = bid >> 3;
    const int z = slot / 24, pos = slot % 24;
    const int yt = (xcd & 3)*4 + pos/6;            // 0..15
    const int xt = (xcd >> 2)*6 + pos%6;           // 0..11
    const int row0 = yt*128, col0 = xt*128;
    if (tid < 128) {
        float s = 0.f;
        #pragma unroll
        for (int t = 0; t < 16; t++)
            s += lpart[(size_t)t*MTOT + (size_t)z*SEQ + row0 + tid];
        ls[tid] = s;
    }
    f32x4 acc[4][4];
    #pragma unroll
    for (int i = 0; i < 4; i++)
        #pragma unroll
        for (int j = 0; j < 4; j++)
            acc[i][j] = (f32x4){0.f,0.f,0.f,0.f};
    mfma_direct<4>(P + ((size_t)z*SEQ + row0)*SEQ, SEQ, vT + ((size_t)z*INTER + col0)*SEQ, SEQ,
                   acc, tid, SEQ);
    EPILOG_IDX
    #pragma unroll
    for (int j = 0; j < 4; j++) {
        int nl = wn + j*16 + cn;
        #pragma unroll
        for (int i = 0; i < 4; i++) {
            #pragma unroll
            for (int r = 0; r < 4; r++) {
                int rowl = wm + i*16 + r4 + r;
                smem[rowl*CS + nl] = f2bfbits(acc[i][j][r]);
            }
        }
    }
    __syncthreads();
    #pragma unroll
    for (int rnd = 0; rnd < 8; rnd++) {
        int row = rnd*16 + (tid>>4);
        int col = (tid&15)*8;
        int m = z*SEQ + row0 + row;
        float linv = 1.0f / ls[row];
        u16x8 cx = *(const u16x8*)&smem[row*CS + col];
        size_t idx = (size_t)m*INTER + col0 + col;
        u16x8 uu = *(const u16x8*)&u[idx];
        u16x8 g;
        #pragma unroll
        for (int t = 0; t < 8; t++)
            g[t] = f2bfbits(bfbits2f(uu[t]) * bfbits2f(cx[t]) * linv);
        *(u16x8*)&u[idx] = g;
    }
}

// ---- K4: out = g@Wo + bo. 128x64 tile, grid 768 = 3/CU balanced, no LDS ----
__global__ __launch_bounds__(256) void gemm2_mfma(
    const unsigned short* __restrict__ g, const unsigned short* __restrict__ WoT,
    const float* __restrict__ bo, float* __restrict__ out)
{
    const int tid = threadIdx.x;
    const int bid = blockIdx.x;
    const int xcd = bid & 7, slot = bid >> 3;      // slot in [0,96)
    const int xt = slot >> 3;                      // 0..11
    const int yt = (xcd << 3) + (slot & 7);        // 0..63
    const int row0 = yt*128, col0 = xt*64;
    f32x4 acc[4][2];
    #pragma unroll
    for (int i = 0; i < 4; i++)
        #pragma unroll
        for (int j = 0; j < 2; j++)
            acc[i][j] = (f32x4){0.f,0.f,0.f,0.f};
    mfma_direct<2>(g + (size_t)row0*INTER, INTER, WoT + (size_t)col0*INTER, INTER,
                   acc, tid, INTER);
    const int lane = tid & 63, wave = tid >> 6;
    const int wm = (wave >> 1) << 6;
    const int wn = (wave & 1) << 5;
    const int cn = lane & 15, r4 = (lane >> 4) << 2;
    #pragma unroll
    for (int j = 0; j < 2; j++) {
        int n = col0 + wn + j*16 + cn;
        float bon = bo[n];
        #pragma unroll
        for (int i = 0; i < 4; i++) {
            #pragma unroll
            for (int r = 0; r < 4; r++) {
                int m = row0 + wm + i*16 + r4 + r;
                out[(size_t)m*HIDDEN + n] = acc[i][j][r] + bon;
            }
        }
    }
}

extern "C" void kernel_launch(void* const* d_in, const int* in_sizes, int n_in,
                              void* d_out, int out_size, void* d_ws, size_t ws_size,
                              hipStream_t stream)
{
    const float* X     = (const float*)d_in[0];
    const int*   mask  = (const int*)d_in[1];
    const float* Wi    = (const float*)d_in[3];
    const float* bi    = (const float*)d_in[4];
    const float* gamma = (const float*)d_in[5];
    const float* beta  = (const float*)d_in[6];
    const float* Wo    = (const float*)d_in[7];
    const float* bo    = (const float*)d_in[8];
    float* out = (float*)d_out;

    unsigned short* Xb  = (unsigned short*)d_ws;            // 8192*768
    unsigned short* WiT = Xb  + (size_t)MTOT*HIDDEN;        // 3200*768
    unsigned short* WoT = WiT + (size_t)ETOT*HIDDEN;        // 768*1536
    unsigned short* u   = WoT + (size_t)HIDDEN*INTER;       // 8192*1536
    unsigned short* vT  = u   + (size_t)MTOT*INTER;         // 4*1536*2048
    unsigned short* qb  = vT  + (size_t)MTOT*INTER;         // 8192*128
    unsigned short* kb  = qb  + (size_t)MTOT*KEY;           // 8192*128
    unsigned short* P   = kb  + (size_t)MTOT*KEY;           // 4*2048*2048
    float* scb   = (float*)(P + (size_t)NB*SEQ*SEQ);        // 4 (+pad)
    float* lpart = scb + 8;                                 // 16*8192

    prep_kernel<<<6628, 256, 0, stream>>>(X, Wi, Wo, mask, Xb, WiT, WoT, scb);
    gemm1_mfma<<<1600, 256, 0, stream>>>(Xb, WiT, bi, gamma, beta, u, vT, qb, kb);
    attn_mfma<<<dim3(SEQ/128, SEQ/128, NB), 256, 0, stream>>>(qb, kb, mask, scb, P, lpart);
    pv_mfma<<<768, 256, 0, stream>>>(P, vT, lpart, u);
    gemm2_mfma<<<768, 256, 0, stream>>>(u, WoT, bo, out);
}

// Round 9
// 267.146 us; speedup vs baseline: 2.0890x; 2.0890x over previous
//
#include <hip/hip_runtime.h>
#include <math.h>

#define HIDDEN 768
#define KEY    128
#define INTER  1536
#define NB     4
#define SEQ    2048
#define MTOT   (NB*SEQ)          // 8192
#define ETOT   (2*INTER+KEY)     // 3200
#define CS     136               // C-tile LDS stride in halfwords

typedef short bf16x8 __attribute__((ext_vector_type(8)));
typedef float f32x4  __attribute__((ext_vector_type(4)));
typedef unsigned short u16x8 __attribute__((ext_vector_type(8)));

__device__ __forceinline__ unsigned short f2bfbits(float x) {
    union { float f; unsigned int u; } a; a.f = x;
    unsigned int r = a.u + 0x7fffu + ((a.u >> 16) & 1u);
    return (unsigned short)(r >> 16);
}
__device__ __forceinline__ float bfbits2f(unsigned short b) {
    union { float f; unsigned int u; } a; a.u = ((unsigned int)b) << 16;
    return a.f;
}

__device__ __forceinline__ void gl2lds16(const unsigned short* g, unsigned short* l) {
    __builtin_amdgcn_global_load_lds(
        (const __attribute__((address_space(1))) unsigned int*)g,
        (__attribute__((address_space(3))) unsigned int*)l, 16, 0, 0);
}

// ---- fused prologue: X->bf16, Wi^T, Wo^T, per-batch scale ----
__device__ __forceinline__ void transpose_tile(
    const float* __restrict__ in, unsigned short* __restrict__ out,
    int R, int C, int c0, int r0, int tid, unsigned short tile[32][33])
{
    int tx = tid & 31, ty4 = (tid >> 5)*4;
    #pragma unroll
    for (int rr = 0; rr < 4; rr++) {
        int r = ty4 + rr;
        tile[r][tx] = f2bfbits(in[(size_t)(r0+r)*C + c0+tx]);
    }
    __syncthreads();
    #pragma unroll
    for (int rr = 0; rr < 4; rr++) {
        int r = ty4 + rr;
        out[(size_t)(c0+r)*R + r0+tx] = tile[tx][r];
    }
}

__global__ __launch_bounds__(256) void prep_kernel(
    const float* __restrict__ X, const float* __restrict__ Wi,
    const float* __restrict__ Wo, const int* __restrict__ mask,
    unsigned short* __restrict__ Xb, unsigned short* __restrict__ WiT,
    unsigned short* __restrict__ WoT, float* __restrict__ scaleb)
{
    __shared__ unsigned short tile[32][33];
    __shared__ int red[256];
    const int bid = blockIdx.x, tid = threadIdx.x;
    if (bid < 3072) {                          // X -> bf16, 8 elems/thread
        int i = bid*256 + tid;
        const float4* in4 = (const float4*)X;
        float4 a = in4[(size_t)i*2], b = in4[(size_t)i*2+1];
        u16x8 o;
        o[0]=f2bfbits(a.x); o[1]=f2bfbits(a.y); o[2]=f2bfbits(a.z); o[3]=f2bfbits(a.w);
        o[4]=f2bfbits(b.x); o[5]=f2bfbits(b.y); o[6]=f2bfbits(b.z); o[7]=f2bfbits(b.w);
        *(u16x8*)&Xb[(size_t)i*8] = o;
    } else if (bid < 5472) {                   // Wi [768][3200] -> WiT [3200][768]
        int t = bid - 3072;
        transpose_tile(Wi, WiT, HIDDEN, ETOT, (t%100)*32, (t/100)*32, tid, tile);
    } else if (bid < 6624) {                   // Wo [1536][768] -> WoT [768][1536]
        int t = bid - 5472;
        transpose_tile(Wo, WoT, INTER, HIDDEN, (t%24)*32, (t/24)*32, tid, tile);
    } else {                                   // per-batch softmax length scale
        int b = bid - 6624;
        int s = 0;
        for (int j = tid; j < SEQ; j += 256)
            s += (mask[b*SEQ + j] != 0) ? 1 : 0;
        red[tid] = s;
        __syncthreads();
        for (int step = 128; step > 0; step >>= 1) {
            if (tid < step) red[tid] += red[tid + step];
            __syncthreads();
        }
        if (tid == 0) {
            float l = fmaxf((float)red[0], 1.0f);
            scaleb[b] = logf(l) / logf(512.0f);
        }
    }
}

// ---- shared MFMA K-loop: 128x128 tile, templated BK (32 or 64) ----
template<int BK>
__device__ __forceinline__ void mfma_core(
    const unsigned short* __restrict__ Abase, int lda,
    const unsigned short* __restrict__ Bbase, int ldb,
    unsigned short* As, unsigned short* Bs,
    f32x4 acc[4][4], int tid, int ktot)
{
    const int lane = tid & 63, wave = tid >> 6;
    const int wm = (wave >> 1) << 6, wn = (wave & 1) << 6;
    const int lm = lane & 15;
    const int q8 = (lane >> 4) << 3;
    const int row_a = tid >> 2, col_a = (tid & 3) << 3;
    const int row_b = row_a + 64;

    for (int k0 = 0; k0 < ktot; k0 += BK) {
        if (k0) __syncthreads();
        #pragma unroll
        for (int h = 0; h < BK/32; h++) {
            gl2lds16(Abase + (size_t)row_a*lda + k0 + h*32 + col_a, As + h*4096 + tid*8);
            gl2lds16(Abase + (size_t)row_b*lda + k0 + h*32 + col_a, As + h*4096 + (tid+256)*8);
            gl2lds16(Bbase + (size_t)row_a*ldb + k0 + h*32 + col_a, Bs + h*4096 + tid*8);
            gl2lds16(Bbase + (size_t)row_b*ldb + k0 + h*32 + col_a, Bs + h*4096 + (tid+256)*8);
        }
        __syncthreads();
        #pragma unroll
        for (int h = 0; h < BK/32; h++) {
            const unsigned short* Ah = As + h*4096;
            const unsigned short* Bh = Bs + h*4096;
            bf16x8 af[4], bfr[4];
            #pragma unroll
            for (int i = 0; i < 4; i++)
                af[i] = *(const bf16x8*)&Ah[(wm + i*16 + lm)*32 + q8];
            #pragma unroll
            for (int j = 0; j < 4; j++)
                bfr[j] = *(const bf16x8*)&Bh[(wn + j*16 + lm)*32 + q8];
            #pragma unroll
            for (int i = 0; i < 4; i++)
                #pragma unroll
                for (int j = 0; j < 4; j++)
                    acc[i][j] = __builtin_amdgcn_mfma_f32_16x16x32_bf16(af[i], bfr[j], acc[i][j], 0, 0, 0);
        }
    }
}

#define EPILOG_IDX \
    const int lane = tid & 63, wave = tid >> 6; \
    const int wm = (wave >> 1) << 6, wn = (wave & 1) << 6; \
    const int cn = lane & 15, r4 = (lane >> 4) << 2;

// ---- K1: h = silu(X@Wi + bi); u row-major, vT transposed, q/k. BK=32 ----
// 1D grid 1600, XCD swizzle: 8-row strip per XCD, x-outer/y-inner.
// __launch_bounds__(256,4): force 128-reg budget -> 4 blocks/CU resident.
__global__ __launch_bounds__(256, 4) void gemm1_mfma(
    const unsigned short* __restrict__ Xb, const unsigned short* __restrict__ WiT,
    const float* __restrict__ bi, const float* __restrict__ gamma, const float* __restrict__ beta,
    unsigned short* __restrict__ u, unsigned short* __restrict__ vT,
    unsigned short* __restrict__ qb, unsigned short* __restrict__ kb)
{
    __shared__ __align__(16) unsigned short smem[128*CS];
    unsigned short* As = smem;
    unsigned short* Bs = smem + 4096;
    const int tid = threadIdx.x;
    const int bid = blockIdx.x;
    const int xcd = bid & 7, slot = bid >> 3;     // slot in [0,200)
    const int xt = slot >> 3;                     // 0..24
    const int yt = (xcd << 3) + (slot & 7);       // 0..63
    const int row0 = yt*128, col0 = xt*128;
    f32x4 acc[4][4];
    #pragma unroll
    for (int i = 0; i < 4; i++)
        #pragma unroll
        for (int j = 0; j < 4; j++)
            acc[i][j] = (f32x4){0.f,0.f,0.f,0.f};
    mfma_core<32>(Xb + (size_t)row0*HIDDEN, HIDDEN, WiT + (size_t)col0*HIDDEN, HIDDEN,
                  As, Bs, acc, tid, HIDDEN);
    EPILOG_IDX
    __syncthreads();
    #pragma unroll
    for (int j = 0; j < 4; j++) {
        int nl = wn + j*16 + cn;
        float bin = bi[col0 + nl];
        #pragma unroll
        for (int i = 0; i < 4; i++) {
            #pragma unroll
            for (int r = 0; r < 4; r++) {
                int rowl = wm + i*16 + r4 + r;
                float x = acc[i][j][r] + bin;
                float h = x / (1.0f + __expf(-x));
                smem[rowl*CS + nl] = f2bfbits(h);
            }
        }
    }
    __syncthreads();
    if (col0 < INTER) {                       // u, row-major
        #pragma unroll
        for (int rnd = 0; rnd < 8; rnd++) {
            int row = rnd*16 + (tid>>4);
            int col = (tid&15)*8;
            u16x8 h = *(const u16x8*)&smem[row*CS + col];
            *(u16x8*)&u[(size_t)(row0+row)*INTER + col0 + col] = h;
        }
    } else if (col0 < 2*INTER) {              // v -> vT[b][INTER][SEQ]
        int c = tid >> 1;
        int half = tid & 1;
        int b = row0 / SEQ;
        int srow = row0 - b*SEQ + half*64;
        size_t base = ((size_t)b*INTER + (col0 - INTER) + c)*SEQ + srow;
        #pragma unroll
        for (int k = 0; k < 8; k++) {
            u16x8 h;
            #pragma unroll
            for (int t = 0; t < 8; t++)
                h[t] = smem[(half*64 + k*8 + t)*CS + c];
            *(u16x8*)&vT[base + k*8] = h;
        }
    } else {                                  // q/k block
        #pragma unroll
        for (int rnd = 0; rnd < 8; rnd++) {
            int row = rnd*16 + (tid>>4);
            int col = (tid&15)*8;
            u16x8 h = *(const u16x8*)&smem[row*CS + col];
            int m = row0 + row;
            u16x8 qo, ko;
            #pragma unroll
            for (int t = 0; t < 8; t++) {
                float hv = bfbits2f(h[t]);
                qo[t] = f2bfbits(hv*gamma[col+t]     + beta[col+t]);
                ko[t] = f2bfbits(hv*gamma[KEY+col+t] + beta[KEY+col+t]);
            }
            *(u16x8*)&qb[(size_t)m*KEY + col] = qo;
            *(u16x8*)&kb[(size_t)m*KEY + col] = ko;
        }
    }
}

// ---- K2: P = exp(scale * q@k^T) masked, bf16 + per-tile partial row sums ----
__global__ __launch_bounds__(256, 4) void attn_mfma(
    const unsigned short* __restrict__ qb, const unsigned short* __restrict__ kb,
    const int* __restrict__ mask, const float* __restrict__ scaleb,
    unsigned short* __restrict__ P, float* __restrict__ lpart)
{
    __shared__ __align__(16) unsigned short smem[128*CS];
    unsigned short* As = smem;
    unsigned short* Bs = smem + 8192;
    const int tid = threadIdx.x;
    const int z = blockIdx.z;
    const int row0 = blockIdx.y*128, col0 = blockIdx.x*128;
    f32x4 acc[4][4];
    #pragma unroll
    for (int i = 0; i < 4; i++)
        #pragma unroll
        for (int j = 0; j < 4; j++)
            acc[i][j] = (f32x4){0.f,0.f,0.f,0.f};
    mfma_core<64>(qb + ((size_t)z*SEQ + row0)*KEY, KEY, kb + ((size_t)z*SEQ + col0)*KEY, KEY,
                  As, Bs, acc, tid, KEY);
    const float st = scaleb[z] * 0.08838834764831845f;
    EPILOG_IDX
    __syncthreads();
    #pragma unroll
    for (int j = 0; j < 4; j++) {
        int nl = wn + j*16 + cn;
        float mkf = (mask[z*SEQ + col0 + nl] != 0) ? 1.0f : 0.0f;
        #pragma unroll
        for (int i = 0; i < 4; i++) {
            #pragma unroll
            for (int r = 0; r < 4; r++) {
                int rowl = wm + i*16 + r4 + r;
                float p = mkf * __expf(acc[i][j][r]*st);
                smem[rowl*CS + nl] = f2bfbits(p);
            }
        }
    }
    __syncthreads();
    #pragma unroll
    for (int rnd = 0; rnd < 8; rnd++) {
        int row = rnd*16 + (tid>>4);
        int col = (tid&15)*8;
        u16x8 h = *(const u16x8*)&smem[row*CS + col];
        *(u16x8*)&P[((size_t)z*SEQ + row0 + row)*SEQ + col0 + col] = h;
        float s8 = 0.f;
        #pragma unroll
        for (int t = 0; t < 8; t++) s8 += bfbits2f(h[t]);
        #pragma unroll
        for (int off = 8; off > 0; off >>= 1) s8 += __shfl_xor(s8, off, 16);
        if ((tid & 15) == 0)
            lpart[(size_t)blockIdx.x*MTOT + (size_t)z*SEQ + row0 + row] = s8;
    }
}

// ---- K3: ctx = P@v / l; g = u*ctx in-place over u. BK=64, XCD 4y x 6x rect ----
__global__ __launch_bounds__(256, 4) void pv_mfma(
    const unsigned short* __restrict__ P, const unsigned short* __restrict__ vT,
    const float* __restrict__ lpart, unsigned short* __restrict__ u)
{
    __shared__ __align__(16) unsigned short smem[128*CS];
    __shared__ float ls[128];
    unsigned short* As = smem;
    unsigned short* Bs = smem + 8192;
    const int tid = threadIdx.x;
    const int bid = blockIdx.x;
    const int xcd = bid & 7, slot = bid >> 3;      // slot in [0,96)
    const int z = slot / 24, pos = slot % 24;
    const int yt = (xcd & 3)*4 + pos/6;            // 0..15
    const int xt = (xcd >> 2)*6 + pos%6;           // 0..11
    const int row0 = yt*128, col0 = xt*128;
    if (tid < 128) {
        float s = 0.f;
        #pragma unroll
        for (int t = 0; t < 16; t++)
            s += lpart[(size_t)t*MTOT + (size_t)z*SEQ + row0 + tid];
        ls[tid] = s;
    }
    f32x4 acc[4][4];
    #pragma unroll
    for (int i = 0; i < 4; i++)
        #pragma unroll
        for (int j = 0; j < 4; j++)
            acc[i][j] = (f32x4){0.f,0.f,0.f,0.f};
    mfma_core<64>(P + ((size_t)z*SEQ + row0)*SEQ, SEQ, vT + ((size_t)z*INTER + col0)*SEQ, SEQ,
                  As, Bs, acc, tid, SEQ);
    EPILOG_IDX
    __syncthreads();
    #pragma unroll
    for (int j = 0; j < 4; j++) {
        int nl = wn + j*16 + cn;
        #pragma unroll
        for (int i = 0; i < 4; i++) {
            #pragma unroll
            for (int r = 0; r < 4; r++) {
                int rowl = wm + i*16 + r4 + r;
                smem[rowl*CS + nl] = f2bfbits(acc[i][j][r]);
            }
        }
    }
    __syncthreads();
    #pragma unroll
    for (int rnd = 0; rnd < 8; rnd++) {
        int row = rnd*16 + (tid>>4);
        int col = (tid&15)*8;
        int m = z*SEQ + row0 + row;
        float linv = 1.0f / ls[row];
        u16x8 cx = *(const u16x8*)&smem[row*CS + col];
        size_t idx = (size_t)m*INTER + col0 + col;
        u16x8 uu = *(const u16x8*)&u[idx];
        u16x8 g;
        #pragma unroll
        for (int t = 0; t < 8; t++)
            g[t] = f2bfbits(bfbits2f(uu[t]) * bfbits2f(cx[t]) * linv);
        *(u16x8*)&u[idx] = g;
    }
}

// ---- K4: out = g@Wo + bo. 128x64 tile, BK=64, grid 768 = 3/CU balanced ----
__global__ __launch_bounds__(256, 4) void gemm2_mfma(
    const unsigned short* __restrict__ g, const unsigned short* __restrict__ WoT,
    const float* __restrict__ bo, float* __restrict__ out)
{
    __shared__ __align__(16) unsigned short As[8192];   // 128 x 32 x 2 substages
    __shared__ __align__(16) unsigned short Bs[4096];   // 64 x 32 x 2 substages
    const int tid = threadIdx.x;
    const int bid = blockIdx.x;
    const int xcd = bid & 7, slot = bid >> 3;      // slot in [0,96)
    const int xt = slot >> 3;                      // 0..11
    const int yt = (xcd << 3) + (slot & 7);        // 0..63
    const int row0 = yt*128, col0 = xt*64;
    const int lane = tid & 63, wave = tid >> 6;
    const int wm = (wave >> 1) << 6;               // 0 or 64
    const int wn = (wave & 1) << 5;                // 0 or 32
    const int lm = lane & 15;
    const int q8 = (lane >> 4) << 3;
    const int row_a = tid >> 2, col_a = (tid & 3) << 3;
    f32x4 acc[4][2];
    #pragma unroll
    for (int i = 0; i < 4; i++)
        #pragma unroll
        for (int j = 0; j < 2; j++)
            acc[i][j] = (f32x4){0.f,0.f,0.f,0.f};
    const unsigned short* Abase = g + (size_t)row0*INTER;
    const unsigned short* Bbase = WoT + (size_t)col0*INTER;
    for (int k0 = 0; k0 < INTER; k0 += 64) {
        if (k0) __syncthreads();
        #pragma unroll
        for (int h = 0; h < 2; h++) {
            gl2lds16(Abase + (size_t)row_a*INTER + k0 + h*32 + col_a,      As + h*4096 + tid*8);
            gl2lds16(Abase + (size_t)(row_a+64)*INTER + k0 + h*32 + col_a, As + h*4096 + (tid+256)*8);
            gl2lds16(Bbase + (size_t)row_a*INTER + k0 + h*32 + col_a,      Bs + h*2048 + tid*8);
        }
        __syncthreads();
        #pragma unroll
        for (int h = 0; h < 2; h++) {
            const unsigned short* Ah = As + h*4096;
            const unsigned short* Bh = Bs + h*2048;
            bf16x8 af[4], bfr[2];
            #pragma unroll
            for (int i = 0; i < 4; i++)
                af[i] = *(const bf16x8*)&Ah[(wm + i*16 + lm)*32 + q8];
            #pragma unroll
            for (int j = 0; j < 2; j++)
                bfr[j] = *(const bf16x8*)&Bh[(wn + j*16 + lm)*32 + q8];
            #pragma unroll
            for (int i = 0; i < 4; i++)
                #pragma unroll
                for (int j = 0; j < 2; j++)
                    acc[i][j] = __builtin_amdgcn_mfma_f32_16x16x32_bf16(af[i], bfr[j], acc[i][j], 0, 0, 0);
        }
    }
    const int cn = lane & 15, r4 = (lane >> 4) << 2;
    #pragma unroll
    for (int j = 0; j < 2; j++) {
        int n = col0 + wn + j*16 + cn;
        float bon = bo[n];
        #pragma unroll
        for (int i = 0; i < 4; i++) {
            #pragma unroll
            for (int r = 0; r < 4; r++) {
                int m = row0 + wm + i*16 + r4 + r;
                out[(size_t)m*HIDDEN + n] = acc[i][j][r] + bon;
            }
        }
    }
}

extern "C" void kernel_launch(void* const* d_in, const int* in_sizes, int n_in,
                              void* d_out, int out_size, void* d_ws, size_t ws_size,
                              hipStream_t stream)
{
    const float* X     = (const float*)d_in[0];
    const int*   mask  = (const int*)d_in[1];
    const float* Wi    = (const float*)d_in[3];
    const float* bi    = (const float*)d_in[4];
    const float* gamma = (const float*)d_in[5];
    const float* beta  = (const float*)d_in[6];
    const float* Wo    = (const float*)d_in[7];
    const float* bo    = (const float*)d_in[8];
    float* out = (float*)d_out;

    unsigned short* Xb  = (unsigned short*)d_ws;            // 8192*768
    unsigned short* WiT = Xb  + (size_t)MTOT*HIDDEN;        // 3200*768
    unsigned short* WoT = WiT + (size_t)ETOT*HIDDEN;        // 768*1536
    unsigned short* u   = WoT + (size_t)HIDDEN*INTER;       // 8192*1536
    unsigned short* vT  = u   + (size_t)MTOT*INTER;         // 4*1536*2048
    unsigned short* qb  = vT  + (size_t)MTOT*INTER;         // 8192*128
    unsigned short* kb  = qb  + (size_t)MTOT*KEY;           // 8192*128
    unsigned short* P   = kb  + (size_t)MTOT*KEY;           // 4*2048*2048
    float* scb   = (float*)(P + (size_t)NB*SEQ*SEQ);        // 4 (+pad)
    float* lpart = scb + 8;                                 // 16*8192

    prep_kernel<<<6628, 256, 0, stream>>>(X, Wi, Wo, mask, Xb, WiT, WoT, scb);
    gemm1_mfma<<<1600, 256, 0, stream>>>(Xb, WiT, bi, gamma, beta, u, vT, qb, kb);
    attn_mfma<<<dim3(SEQ/128, SEQ/128, NB), 256, 0, stream>>>(qb, kb, mask, scb, P, lpart);
    pv_mfma<<<768, 256, 0, stream>>>(P, vT, lpart, u);
    gemm2_mfma<<<768, 256, 0, stream>>>(u, WoT, bo, out);
}